// Round 14
// baseline (194.736 us; speedup 1.0000x reference)
//
#include <hip/hip_runtime.h>

#define H 512
#define W 512
#define TGR 36            // staged target rows (32 + 4 halo)
#define TSTRIDE 520       // floats per staged row (8-word pad -> 4 bank classes)
#define NWAVE 8

// Full-wave (64-lane) sum using DPP only — pure VALU. Result in lane 63.
__device__ __forceinline__ float wave_sum_dpp(float x) {
#define DPP_STEP(ctrl)                                                          \
    x += __int_as_float(__builtin_amdgcn_update_dpp(                            \
        0, __float_as_int(x), (ctrl), 0xF, 0xF, true))
    DPP_STEP(0x111);   // row_shr:1
    DPP_STEP(0x112);   // row_shr:2
    DPP_STEP(0x114);   // row_shr:4
    DPP_STEP(0x118);   // row_shr:8
    DPP_STEP(0x142);   // row_bcast:15
    DPP_STEP(0x143);   // row_bcast:31
#undef DPP_STEP
    return x;
}

__device__ __forceinline__ float4 ld4(const float* p) {
    return *reinterpret_cast<const float4*>(p);
}

// Async global->LDS DMA, 16 B/lane, linear dest (base + lane*16).
__device__ __forceinline__ void gl_lds16(const float* g, float* l) {
    __builtin_amdgcn_global_load_lds(
        (const __attribute__((address_space(1))) void*)g,
        (__attribute__((address_space(3))) void*)l,
        16, 0, 0);
}

// Counted vmcnt wait + sched fence (rule #18).
#define WAITV(n) do { asm volatile("s_waitcnt vmcnt(" #n ")" ::: "memory");     \
                      __builtin_amdgcn_sched_barrier(0); } while (0)
#define RAWBAR() asm volatile("s_barrier" ::: "memory")
#define SFENCE() __builtin_amdgcn_sched_barrier(0)

// Kernel 1: 2-phase counted-vmcnt slab kernel (T3/T4 recipe), zero __syncthreads.
// 1024 blocks x 512 thr; block owns 32 rows of one image. Per-wave issue order
// (pinned by sched_barrier): [4 inA][5 lowerDMA][4 upperDMA][4 inB]. Phase A
// computes rows 0..15 behind vmcnt(8) (upper+inB still in flight); phase B
// behind vmcnt(4). Raw s_barrier (no drain) publishes cross-wave DMA rows.
__global__ __launch_bounds__(512, 4)
void dice_partial(const float* __restrict__ in, const float* __restrict__ tg,
                  float* __restrict__ ws, int nblocks) {
    __shared__ __align__(16) float tgs[TGR * TSTRIDE];   // 74880 B -> 2 blocks/CU

    const int tid  = threadIdx.x;
    const int wave = tid >> 6, lane = tid & 63;
    const int yi   = lane >> 5;           // sub-row within wave (0/1)
    const int lx   = lane & 31;
    const int cc0  = lx * 16;             // my 16 columns: cc0..cc0+15

    // Bijective XCD chunking (1024 % 8 == 0).
    const int bid = blockIdx.x;
    const int wrk = (bid & 7) * (nblocks >> 3) + (bid >> 3);
    const int b   = wrk >> 4;             // image (16 slabs per image)
    const int y0  = (wrk & 15) * 32;      // slab top row
    const float* __restrict__ inb = in + (size_t)b * (H * W);
    const float* __restrict__ tgb = tg + (size_t)b * (H * W);

    // ---- group 1: phase-A input loads (4 events): row y0+2w+yi, 16 px ----
    float4 iA[4];
    {
        const float* rp = inb + (size_t)(y0 + 2 * wave + yi) * W + cc0;
        iA[0] = ld4(rp); iA[1] = ld4(rp + 4); iA[2] = ld4(rp + 8); iA[3] = ld4(rp + 12);
    }
    SFENCE();

    // ---- group 2: lower DMA (5 events): staged rows 0..19 ----
#pragma unroll
    for (int k = 0; k < 5; ++k) {
        const int c = wave * 5 + k, rr = c >> 1, half = (c & 1) * 256;
        gl_lds16(tgb + (size_t)((y0 - 2 + rr) & (H - 1)) * W + half + lane * 4,
                 &tgs[rr * TSTRIDE + half]);
    }
    SFENCE();

    // ---- group 3: upper DMA (4 events): staged rows 20..35 ----
#pragma unroll
    for (int k = 0; k < 4; ++k) {
        const int c = wave * 4 + k, rr = 20 + (c >> 1), half = (c & 1) * 256;
        gl_lds16(tgb + (size_t)((y0 - 2 + rr) & (H - 1)) * W + half + lane * 4,
                 &tgs[rr * TSTRIDE + half]);
    }
    SFENCE();

    // ---- group 4: phase-B input loads (4 events): row y0+16+2w+yi ----
    float4 iB[4];
    {
        const float* rp = inb + (size_t)(y0 + 16 + 2 * wave + yi) * W + cc0;
        iB[0] = ld4(rp); iB[1] = ld4(rp + 4); iB[2] = ld4(rp + 8); iB[3] = ld4(rp + 12);
    }
    SFENCE();

    float acc[25];
#pragma unroll
    for (int k = 0; k < 25; ++k) acc[k] = 0.f;
    float isum = 0.f, tsum = 0.f;
    float iv[16];

    // Consume one phase: input row = base+2w+yi (iv), staged rows base+2w+yi+k.
#define PHASE(base) {                                                           \
        _Pragma("unroll")                                                       \
        for (int k = 0; k < 5; ++k) {                                           \
            const float* rowp = &tgs[((base) + 2 * wave + yi + k) * TSTRIDE];   \
            float tw[20];      /* tw[c] = tg col cc0 + c - 2 (wrapped) */       \
            const float4 m2 = ld4(rowp + ((cc0 - 4) & (W - 1)));                \
            const float4 f0 = ld4(rowp + cc0);                                  \
            const float4 f1 = ld4(rowp + cc0 + 4);                              \
            const float4 f2 = ld4(rowp + cc0 + 8);                              \
            const float4 f3 = ld4(rowp + cc0 + 12);                             \
            const float4 p2 = ld4(rowp + ((cc0 + 16) & (W - 1)));               \
            tw[0]  = m2.z; tw[1]  = m2.w;                                       \
            tw[2]  = f0.x; tw[3]  = f0.y; tw[4]  = f0.z; tw[5]  = f0.w;         \
            tw[6]  = f1.x; tw[7]  = f1.y; tw[8]  = f1.z; tw[9]  = f1.w;         \
            tw[10] = f2.x; tw[11] = f2.y; tw[12] = f2.z; tw[13] = f2.w;         \
            tw[14] = f3.x; tw[15] = f3.y; tw[16] = f3.z; tw[17] = f3.w;         \
            tw[18] = p2.x; tw[19] = p2.y;                                       \
            if (k == 2) {    /* own row: count each tg element exactly once */  \
                _Pragma("unroll")                                               \
                for (int j = 0; j < 16; ++j) tsum += tw[j + 2];                 \
            }                                                                   \
            _Pragma("unroll")                                                   \
            for (int sx = -2; sx <= 2; ++sx) {                                  \
                _Pragma("unroll")                                               \
                for (int j = 0; j < 16; ++j)                                    \
                    acc[(4 - k) * 5 + (sx + 2)] += iv[j] * tw[j + 2 - sx];      \
            }                                                                   \
        }                                                                       \
    }

    // ---- phase A: wait inA + lower DMA (9 oldest of 17), publish, compute ----
    WAITV(8);
    RAWBAR();
    iv[0]=iA[0].x; iv[1]=iA[0].y; iv[2]=iA[0].z; iv[3]=iA[0].w;
    iv[4]=iA[1].x; iv[5]=iA[1].y; iv[6]=iA[1].z; iv[7]=iA[1].w;
    iv[8]=iA[2].x; iv[9]=iA[2].y; iv[10]=iA[2].z; iv[11]=iA[2].w;
    iv[12]=iA[3].x; iv[13]=iA[3].y; iv[14]=iA[3].z; iv[15]=iA[3].w;
#pragma unroll
    for (int j = 0; j < 16; ++j) isum += iv[j];
    PHASE(0)

    // ---- phase B: wait upper DMA, publish, wait inB (private), compute ----
    WAITV(4);
    RAWBAR();
    WAITV(0);
    iv[0]=iB[0].x; iv[1]=iB[0].y; iv[2]=iB[0].z; iv[3]=iB[0].w;
    iv[4]=iB[1].x; iv[5]=iB[1].y; iv[6]=iB[1].z; iv[7]=iB[1].w;
    iv[8]=iB[2].x; iv[9]=iB[2].y; iv[10]=iB[2].z; iv[11]=iB[2].w;
    iv[12]=iB[3].x; iv[13]=iB[3].y; iv[14]=iB[3].z; iv[15]=iB[3].w;
#pragma unroll
    for (int j = 0; j < 16; ++j) isum += iv[j];
    PHASE(16)
#undef PHASE

    // ---- per-wave DPP reduction, lane 63 stores straight to ws ----
    const int nent = nblocks * NWAVE;
    const int wb = bid * NWAVE + wave;
#pragma unroll
    for (int k = 0; k < 25; ++k) {
        const float v = wave_sum_dpp(acc[k]);
        if (lane == 63) ws[(size_t)k * nent + wb] = v;
    }
    {
        const float v = wave_sum_dpp(isum);
        if (lane == 63) ws[(size_t)25 * nent + wb] = v;
        const float u = wave_sum_dpp(tsum);
        if (lane == 63) ws[(size_t)26 * nent + wb] = u;
    }
}

// Kernel 2: 27 blocks, block k tree-reduces the per-wave partials for quantity k.
__global__ __launch_bounds__(256)
void dice_reduce(const float* __restrict__ ws, float* __restrict__ tot, int nent) {
    __shared__ float red[4];
    const int k = blockIdx.x;
    const int tid = threadIdx.x;
    const float* p = ws + (size_t)k * nent;

    float s = 0.f;
    for (int i = tid; i < nent; i += 256) s += p[i];
    s = wave_sum_dpp(s);
    if ((tid & 63) == 63) red[tid >> 6] = s;
    __syncthreads();
    if (tid == 0) tot[k] = red[0] + red[1] + red[2] + red[3];
}

// Kernel 3: one wave — 25-way max + final loss scalar.
__global__ void dice_out(const float* __restrict__ tot, float* __restrict__ out) {
    const int tid = threadIdx.x;   // blockDim = 64
    float v = (tid < 25) ? tot[tid] : -1e30f;
#pragma unroll
    for (int off = 32; off; off >>= 1) v = fmaxf(v, __shfl_down(v, off, 64));
    if (tid == 0) {
        const float denom = tot[25] + tot[26] + 1.0f;   // i_sum + t_sum + SMOOTH
        out[0] = 1.0f - (2.0f * v + 1.0f) / denom;      // min loss == max intersection
    }
}

extern "C" void kernel_launch(void* const* d_in, const int* in_sizes, int n_in,
                              void* d_out, int out_size, void* d_ws, size_t ws_size,
                              hipStream_t stream) {
    const float* inputs  = (const float*)d_in[0];
    const float* targets = (const float*)d_in[1];
    float* out = (float*)d_out;
    float* ws  = (float*)d_ws;

    const int B = in_sizes[0] / (H * W);      // 64
    const int nblocks = B * 16;               // 1024 slabs of 32 rows
    const int nent = nblocks * NWAVE;         // 8192 per quantity

    float* tot = ws + (size_t)27 * nent;      // 27 totals after the table

    dice_partial<<<nblocks, 512, 0, stream>>>(inputs, targets, ws, nblocks);
    dice_reduce<<<27, 256, 0, stream>>>(ws, tot, nent);
    dice_out<<<1, 64, 0, stream>>>(tot, out);
}

// Round 15
// 54.984 us; speedup vs baseline: 3.5417x; 3.5417x over previous
//
#include <hip/hip_runtime.h>

#define H 512
#define W 512
#define SLAB 32             // rows per slab
#define TGR  36             // staged target rows per slab (+-2 halo)
#define NSLAB 4             // slabs per block (128 rows)
#define NWAVE 8

// Full-wave (64-lane) sum using DPP only — pure VALU. Result in lane 63.
__device__ __forceinline__ float wave_sum_dpp(float x) {
#define DPP_STEP(ctrl)                                                          \
    x += __int_as_float(__builtin_amdgcn_update_dpp(                            \
        0, __float_as_int(x), (ctrl), 0xF, 0xF, true))
    DPP_STEP(0x111);   // row_shr:1
    DPP_STEP(0x112);   // row_shr:2
    DPP_STEP(0x114);   // row_shr:4
    DPP_STEP(0x118);   // row_shr:8
    DPP_STEP(0x142);   // row_bcast:15
    DPP_STEP(0x143);   // row_bcast:31
#undef DPP_STEP
    return x;
}

__device__ __forceinline__ float4 ld4(const float* p) {
    return *reinterpret_cast<const float4*>(p);
}
__device__ __forceinline__ float2 ld2(const float* p) {
    return *reinterpret_cast<const float2*>(p);
}

// Async global->LDS DMA, 16 B/lane, linear dest (base + lane*16).
__device__ __forceinline__ void gl_lds16(const float* g, float* l) {
    __builtin_amdgcn_global_load_lds(
        (const __attribute__((address_space(1))) void*)g,
        (__attribute__((address_space(3))) void*)l,
        16, 0, 0);
}

// Kernel 1: 2-phase DMA slab pipeline, stage-EARLY/compute-late (R12 idea,
// R8 body, no unroll, spill headroom). 256 blocks (1/CU), 512 thr; block owns
// 128 rows of one image = 4 slabs of 32 rows. Loop: [inputs(s)->regs]
// [DMA(s+1)->buf^1] [compute(s) from buf] [__syncthreads: drains DMA s+1,
// which has been in flight for the whole compute phase].
__global__ __launch_bounds__(512, 2)
void dice_partial(const float* __restrict__ in, const float* __restrict__ tg,
                  float* __restrict__ ws, int nblocks) {
    __shared__ __align__(16) float buf[2][TGR * W];   // 2 x 72 KB
    __shared__ float warr[NWAVE][32];

    const int tid  = threadIdx.x;
    const int wave = tid >> 6, lane = tid & 63;

    // Bijective XCD chunking (256 % 8 == 0); an image's 4 blocks share an XCD.
    const int bid = blockIdx.x;
    const int wrk = (bid & 7) * (nblocks >> 3) + (bid >> 3);
    const int b   = wrk >> 2;              // image (4 blocks per image)
    const int r0  = (wrk & 3) * (NSLAB * SLAB);   // region top row
    const float* __restrict__ inb = in + (size_t)b * (H * W);
    const float* __restrict__ tgb = tg + (size_t)b * (H * W);

    const int c0 = lane * 8;               // my 8 columns

    // 72 DMA events per slab (36 rows x 2 halves), 9 per wave.
#define STAGE(s, sb) {                                                          \
        const int y0s = r0 + (s) * SLAB;                                        \
        _Pragma("unroll")                                                       \
        for (int k = 0; k < 9; ++k) {                                           \
            const int c    = wave * 9 + k;                                      \
            const int rr   = c >> 1;                                            \
            const int half = (c & 1) * 256;                                     \
            gl_lds16(tgb + (size_t)((y0s - 2 + rr) & (H - 1)) * W + half        \
                         + lane * 4,                                            \
                     &buf[sb][rr * W + half]);                                  \
        }                                                                       \
    }

    float acc[25];
#pragma unroll
    for (int k = 0; k < 25; ++k) acc[k] = 0.f;
    float isum = 0.f, tsum = 0.f;

    STAGE(0, 0)
    __syncthreads();                       // prologue fill (once per block)

#pragma unroll 1
    for (int s = 0; s < NSLAB; ++s) {
        const int sb = s & 1;
        const int ry = r0 + s * SLAB + wave * 4;    // this wave's input rows

        // ---- inputs for slab s -> registers (issued before next-slab DMA) ----
        float4 ia[4], ic[4];
#pragma unroll
        for (int yi = 0; yi < 4; ++yi) {
            const float* rp = inb + (size_t)(ry + yi) * W;
            ia[yi] = ld4(rp + c0);
            ic[yi] = ld4(rp + c0 + 4);
        }

        // ---- next slab's target DMA: in flight during this compute phase ----
        if (s + 1 < NSLAB) STAGE(s + 1, sb ^ 1)

        // ---- compute slab s (R8's verified body) ----
        float iv[4][8];
#pragma unroll
        for (int yi = 0; yi < 4; ++yi) {
            iv[yi][0] = ia[yi].x; iv[yi][1] = ia[yi].y;
            iv[yi][2] = ia[yi].z; iv[yi][3] = ia[yi].w;
            iv[yi][4] = ic[yi].x; iv[yi][5] = ic[yi].y;
            iv[yi][6] = ic[yi].z; iv[yi][7] = ic[yi].w;
#pragma unroll
            for (int j = 0; j < 8; ++j) isum += iv[yi][j];
        }

#pragma unroll
        for (int t = 0; t < 8; ++t) {
            const float* rowp = &buf[sb][(wave * 4 + t) * W];
            float tw[12];                  // tw[c] = target col c0 + c - 2
            const float4 a  = ld4(rowp + c0);
            const float4 cc = ld4(rowp + c0 + 4);
            const float2 lf = ld2(rowp + ((c0 - 2) & (W - 1)));
            const float2 rg = ld2(rowp + ((c0 + 8) & (W - 1)));
            tw[0]  = lf.x; tw[1]  = lf.y;
            tw[2]  = a.x;  tw[3]  = a.y;  tw[4] = a.z;  tw[5] = a.w;
            tw[6]  = cc.x; tw[7]  = cc.y; tw[8] = cc.z; tw[9] = cc.w;
            tw[10] = rg.x; tw[11] = rg.y;

            if (t >= 2 && t <= 5) {        // own rows: count each tg elem once
#pragma unroll
                for (int j = 0; j < 8; ++j) tsum += tw[j + 2];
            }

#pragma unroll
            for (int yi = 0; yi < 4; ++yi) {
                const int sy = yi + 2 - t;
                if (sy < -2 || sy > 2) continue;   // 20 live pairs
#pragma unroll
                for (int sx = -2; sx <= 2; ++sx) {
#pragma unroll
                    for (int j = 0; j < 8; ++j)
                        acc[(sy + 2) * 5 + (sx + 2)] += iv[yi][j] * tw[j + 2 - sx];
                }
            }
        }

        __syncthreads();   // drains DMA(s+1) — hidden under the compute above
    }
#undef STAGE

    // ---- once per block: DPP-reduce 27 quantities ----
#pragma unroll
    for (int k = 0; k < 25; ++k) {
        const float v = wave_sum_dpp(acc[k]);
        if (lane == 63) warr[wave][k] = v;
    }
    {
        const float v = wave_sum_dpp(isum);
        if (lane == 63) warr[wave][25] = v;
        const float u = wave_sum_dpp(tsum);
        if (lane == 63) warr[wave][26] = u;
    }

    __syncthreads();
    if (tid < 27) {
        float s = 0.f;
#pragma unroll
        for (int w = 0; w < NWAVE; ++w) s += warr[w][tid];
        ws[tid * nblocks + bid] = s;       // [k][block] for coalesced pass 2
    }
}

// Kernel 2: 27 blocks, block k tree-reduces the per-block partials for quantity k.
__global__ __launch_bounds__(256)
void dice_reduce(const float* __restrict__ ws, float* __restrict__ tot, int nblocks) {
    __shared__ float red[4];
    const int k = blockIdx.x;
    const int tid = threadIdx.x;
    const float* p = ws + (size_t)k * nblocks;

    float s = 0.f;
    for (int i = tid; i < nblocks; i += 256) s += p[i];
    s = wave_sum_dpp(s);
    if ((tid & 63) == 63) red[tid >> 6] = s;
    __syncthreads();
    if (tid == 0) tot[k] = red[0] + red[1] + red[2] + red[3];
}

// Kernel 3: one wave — 25-way max + final loss scalar.
__global__ void dice_out(const float* __restrict__ tot, float* __restrict__ out) {
    const int tid = threadIdx.x;   // blockDim = 64
    float v = (tid < 25) ? tot[tid] : -1e30f;
#pragma unroll
    for (int off = 32; off; off >>= 1) v = fmaxf(v, __shfl_down(v, off, 64));
    if (tid == 0) {
        const float denom = tot[25] + tot[26] + 1.0f;   // i_sum + t_sum + SMOOTH
        out[0] = 1.0f - (2.0f * v + 1.0f) / denom;      // min loss == max intersection
    }
}

extern "C" void kernel_launch(void* const* d_in, const int* in_sizes, int n_in,
                              void* d_out, int out_size, void* d_ws, size_t ws_size,
                              hipStream_t stream) {
    const float* inputs  = (const float*)d_in[0];
    const float* targets = (const float*)d_in[1];
    float* out = (float*)d_out;
    float* ws  = (float*)d_ws;

    const int B = in_sizes[0] / (H * W);      // 64
    const int nblocks = B * 4;                // 256 blocks (1 per CU), 128 rows each

    float* tot = ws + (size_t)27 * nblocks;   // 27 totals after the table

    dice_partial<<<nblocks, 512, 0, stream>>>(inputs, targets, ws, nblocks);
    dice_reduce<<<27, 256, 0, stream>>>(ws, tot, nblocks);
    dice_out<<<1, 64, 0, stream>>>(tot, out);
}